// Round 10
// baseline (3104.512 us; speedup 1.0000x reference)
//
#include <hip/hip_runtime.h>
#include <stdint.h>

// Fence-free dataflow-pipelined persistent LSTM, MI355X — v8 "fat WG".
// v7c (2159 us, PASS) -> v8: same 4-group pipeline & proven v6/v7c sync tail,
// but 32 WGs per group x 96 output cols (was 64 x 48) -> 128 CUs active:
//  - chip A-traffic halves (32 dup readers of h per group, was 64);
//  - flag fan-in halves (8 producers/wave, was 16); half the pollers;
//  - per-CU MFMA duty doubles (192 MFMA/step) -> counter-evidence says the
//    clock is DPM-depressed (~0.85 GHz) at 7% util; denser work should hold a
//    higher DPM state and shrink every latency term on the serial chain.
// Weights register-resident: Breg[6][8] = 192 VGPR/wave (layer groups).
// Sync semantics: RELAXED agent atomics only; cross-WG data via sc1
// write-through stores drained (waitcnt 0 + barrier) before tid0 flag store;
// h/x read via normal cached loads at never-touched addresses; P rings via
// atomic loads. f-gate dead code -> [i|g|o] = 96 gate rows per 32 units.

#define T_STEPS 256
#define HDIM    1024
#define NB      64
#define INDIM   512
#define NWG     128
#define TPB     256
#define PRING   8

typedef _Float16 f16;
typedef __attribute__((ext_vector_type(8))) _Float16 f16x8;
typedef __attribute__((ext_vector_type(4))) float    f32x4;

// ws byte offsets (layout unchanged from v7c; P rings same footprint)
#define CNT_OFF 0            // proCnt @0; WG flags @ +64B: [4][32] ints, 64B stride
#define XB_OFF  81920        // f16 [256][64][512]   x, time-major
#define H0_OFF  16859136     // f16 [257][64][1024]  slot t = h0_{t-1}
#define H1_OFF  50544640     // f16 [257][64][1024]  slot t = h1_{t-1}
#define C0_OFF  84230144     // f32 [64][1024]
#define C1_OFF  84492288     // f32 [64][1024]
#define P0_OFF  84754432     // f32 [8][64][3072]    ring, [slot][m][col]
#define P1_OFF  91045888     // f32 [8][64][3072]
// end 97337344

__device__ __forceinline__ float sigm(float x)     { return 1.0f / (1.0f + __expf(-x)); }
__device__ __forceinline__ float tanhfast(float x) { float e = __expf(2.0f * x); return 1.0f - 2.0f / (e + 1.0f); }

__device__ __forceinline__ void arrive(int* c) {
  __hip_atomic_fetch_add(c, 1, __ATOMIC_RELAXED, __HIP_MEMORY_SCOPE_AGENT);
}
__device__ __forceinline__ void wait_ge(int* c, int v) {
  while (__hip_atomic_load(c, __ATOMIC_RELAXED, __HIP_MEMORY_SCOPE_AGENT) < v)
    __builtin_amdgcn_s_sleep(1);
  __atomic_signal_fence(__ATOMIC_ACQUIRE);
}
__device__ __forceinline__ void sti(int* p, int v) {
  __hip_atomic_store(p, v, __ATOMIC_RELAXED, __HIP_MEMORY_SCOPE_AGENT);
}
__device__ __forceinline__ void st2h(f16* p, float a, float b) {
  union { f16 h[2]; uint32_t u; } cc; cc.h[0] = (f16)a; cc.h[1] = (f16)b;
  __hip_atomic_store((uint32_t*)p, cc.u, __ATOMIC_RELAXED, __HIP_MEMORY_SCOPE_AGENT);
}
__device__ __forceinline__ void st8a(void* p, unsigned long long v) {
  __hip_atomic_store((unsigned long long*)p, v, __ATOMIC_RELAXED, __HIP_MEMORY_SCOPE_AGENT);
}
__device__ __forceinline__ unsigned long long ld8(const float* p) {
  return __hip_atomic_load((const unsigned long long*)p, __ATOMIC_RELAXED, __HIP_MEMORY_SCOPE_AGENT);
}
__device__ __forceinline__ f16x8 pack8(f32x4 a, f32x4 b) {
  f16x8 h;
  h[0]=(f16)a[0]; h[1]=(f16)a[1]; h[2]=(f16)a[2]; h[3]=(f16)a[3];
  h[4]=(f16)b[0]; h[5]=(f16)b[1]; h[6]=(f16)b[2]; h[7]=(f16)b[3];
  return h;
}
__device__ __forceinline__ unsigned long long packh4(float a, float b, float c, float d) {
  union { f16 h[4]; unsigned long long u; } hh;
  hh.h[0]=(f16)a; hh.h[1]=(f16)b; hh.h[2]=(f16)c; hh.h[3]=(f16)d;
  return hh.u;
}

// 96x64 tile GEMM: A from global (f16, row stride K), B register-resident.
template<int K>
__device__ __forceinline__ void gemm96(const f16* __restrict__ Aw,
                                       const f16x8 (&B)[6][8],
                                       int lr, f32x4 (&acc)[4][6]) {
  constexpr int NIT = K / 128;                 // per-wave K-quarter, 32/iter
  const f16* a0 = Aw + (size_t)(lr +  0) * K;
  const f16* a1 = Aw + (size_t)(lr + 16) * K;
  const f16* a2 = Aw + (size_t)(lr + 32) * K;
  const f16* a3 = Aw + (size_t)(lr + 48) * K;
#pragma unroll
  for (int it = 0; it < NIT; ++it) {
    const int kk = it * 32;
    f16x8 A0 = *(const f16x8*)(a0 + kk);
    f16x8 A1 = *(const f16x8*)(a1 + kk);
    f16x8 A2 = *(const f16x8*)(a2 + kk);
    f16x8 A3 = *(const f16x8*)(a3 + kk);
#pragma unroll
    for (int nt = 0; nt < 6; ++nt) {
      acc[0][nt] = __builtin_amdgcn_mfma_f32_16x16x32_f16(A0, B[nt][it], acc[0][nt], 0, 0, 0);
      acc[1][nt] = __builtin_amdgcn_mfma_f32_16x16x32_f16(A1, B[nt][it], acc[1][nt], 0, 0, 0);
      acc[2][nt] = __builtin_amdgcn_mfma_f32_16x16x32_f16(A2, B[nt][it], acc[2][nt], 0, 0, 0);
      acc[3][nt] = __builtin_amdgcn_mfma_f32_16x16x32_f16(A3, B[nt][it], acc[3][nt], 0, 0, 0);
    }
  }
}

__global__ __launch_bounds__(TPB, 1) void lstm_pers(
    const float* __restrict__ x,
    const float* __restrict__ Wx0, const float* __restrict__ Wh0,
    const float* __restrict__ b0,  const float* __restrict__ Wc0,
    const float* __restrict__ Wx1, const float* __restrict__ Wh1,
    const float* __restrict__ b1,  const float* __restrict__ Wc1,
    float* __restrict__ out, char* __restrict__ ws)
{
  int* cbase = (int*)(ws + CNT_OFF);
  int* proCnt = cbase;
  auto FLG = [&](int g, int i) { return cbase + 16 + ((g * 32 + i) << 4); };  // 64B stride

  f16* XB   = (f16*)(ws + XB_OFF);
  f16* H0   = (f16*)(ws + H0_OFF);
  f16* H1   = (f16*)(ws + H1_OFF);
  float* C0 = (float*)(ws + C0_OFF);
  float* C1 = (float*)(ws + C1_OFF);
  float* P0b = (float*)(ws + P0_OFF);
  float* P1b = (float*)(ws + P1_OFF);

  __shared__ float lds[4][64][100];    // cross-wave K-partial reduce (102400 B)

  const int tid  = threadIdx.x;
  const int wg   = blockIdx.x;
  const int gtid = wg * TPB + tid;
  const int GSZ  = NWG * TPB;

  const int grp  = wg >> 5;      // 0=P0, 1=L0, 2=P1, 3=L1  (32 WGs each)
  const int ug   = wg & 31;
  const int lane = tid & 63;
  const int wv   = tid >> 6;
  const int quad = lane >> 4;
  const int lr   = lane & 15;

  const float* Wsrc; int K;
  switch (grp) {
    case 0:  Wsrc = Wx0; K = 512;  break;
    case 1:  Wsrc = Wh0; K = 1024; break;
    case 2:  Wsrc = Wx1; K = 1024; break;
    default: Wsrc = Wh1; K = 1024; break;
  }
  const int Kq  = K >> 2;
  const int NIT = K >> 7;        // 4 (K=512) or 8 (K=1024)

  // ---------------- prologue ----------------
  // (a) per-wave weight block -> REGISTERS: 96 rows x K-quarter.
  //     Row map: col-tile nt -> gate nt>>1 (i/g/o), unit (nt&1)*16+lr.
  f16x8 Breg[6][8];
#pragma unroll
  for (int nt = 0; nt < 6; ++nt) {
    const int gate = nt >> 1;
    const int R = ug * 32 + (nt & 1) * 16 + lr
                + (gate == 1 ? 2048 : (gate == 2 ? 3072 : 0));
    const float* wr = Wsrc + (size_t)R * K + wv * Kq + quad * 8;
#pragma unroll
    for (int it = 0; it < 8; ++it) {
      if (it < NIT) {
        f32x4 f0 = *(const f32x4*)(wr + it * 32);
        f32x4 f1 = *(const f32x4*)(wr + it * 32 + 4);
        Breg[nt][it] = pack8(f0, f1);
      } else {
        Breg[nt][it] = (f16x8){};
      }
    }
  }
  // (b) x pack, time-major, proven 4B sc1 atomic pair stores
  for (int idx = gtid; idx < T_STEPS * NB * 256; idx += GSZ) {
    int t = idx >> 14, n = (idx >> 8) & 63, i2 = (idx & 255) << 1;
    const float* src = x + (size_t)n * (T_STEPS * INDIM) + (size_t)t * INDIM + i2;
    st2h(&XB[(size_t)idx << 1], src[0], src[1]);
  }

  // light grid barrier (no cache fences; shared data went through sc1)
  __builtin_amdgcn_s_waitcnt(0);
  __syncthreads();
  if (tid == 0) { arrive(proCnt); wait_ge(proCnt, NWG); }
  __syncthreads();

  // ---------------- persistent 4-group dataflow pipeline ----------------
  float* cst = (grp == 1) ? C0 : C1;
  const int m_e = tid >> 2, j0 = (tid & 3) << 3;   // L-epilogue: 8 units/thread
  const int u0  = ug * 32 + j0;
  float* crow = cst + (size_t)m_e * HDIM + u0;
  const float* bb = (grp == 1) ? b0 : b1;
  const float* wc = (grp == 1) ? Wc0 : Wc1;

  for (int t = 0; t < T_STEPS; ++t) {
    // ---- per-wave composite detect (no barrier; 64B-stride WG flags) ----
    {
      int* myp = nullptr; int tgt = 0;
      if (grp == 0) {
        if (lane == 0 && t >= PRING) { myp = FLG(1, ug); tgt = t - PRING + 1; }
      } else if (grp == 1) {
        if (lane < 8 && t > 0)       { myp = FLG(1, wv * 8 + lane); tgt = t; }
        else if (lane == 8)          { myp = FLG(0, ug); tgt = t + 1; }
      } else if (grp == 2) {
        if (lane < 8)                { myp = FLG(1, wv * 8 + lane); tgt = t + 1; }
        else if (lane == 8 && t >= PRING) { myp = FLG(3, ug); tgt = t - PRING + 1; }
      } else {
        if (lane < 8 && t > 0)       { myp = FLG(3, wv * 8 + lane); tgt = t; }
        else if (lane == 8)          { myp = FLG(2, ug); tgt = t + 1; }
      }
      if (myp) {
        while (__hip_atomic_load(myp, __ATOMIC_RELAXED, __HIP_MEMORY_SCOPE_AGENT) < tgt)
          __builtin_amdgcn_s_sleep(1);
      }
      __atomic_signal_fence(__ATOMIC_ACQUIRE);
    }

    const f16* Abase;
    if (grp == 0)      Abase = XB + (size_t)t * NB * INDIM;          // x_t
    else if (grp == 1) Abase = H0 + (size_t)t * NB * HDIM;           // h0_{t-1}
    else if (grp == 2) Abase = H0 + (size_t)(t + 1) * NB * HDIM;     // h0_t
    else               Abase = H1 + (size_t)t * NB * HDIM;           // h1_{t-1}

    // L-groups: issue P-ring gate loads + c/bias/peephole loads NOW; latency
    // hides under the GEMM below (compiler-managed waitcnt).
    unsigned long long pri[4], prg[4], pro[4];
    f32x4 c4[2], bi[2], bg[2], bo[2], wi[2], wo[2];
    if (grp & 1) {
      const float* Pb = (grp == 1 ? P0b : P1b) + (size_t)(t & (PRING - 1)) * NB * 3072;
      const float* pbase = Pb + (size_t)m_e * 3072 + ug * 96 + j0;
#pragma unroll
      for (int q = 0; q < 4; ++q) {
        pri[q] = ld8(pbase + 2 * q);
        prg[q] = ld8(pbase + 32 + 2 * q);
        pro[q] = ld8(pbase + 64 + 2 * q);
      }
#pragma unroll
      for (int p = 0; p < 2; ++p) {
        c4[p] = *(const f32x4*)(crow + 4 * p);
        bi[p] = *(const f32x4*)(bb + u0 + 4 * p);
        bg[p] = *(const f32x4*)(bb + 2048 + u0 + 4 * p);
        bo[p] = *(const f32x4*)(bb + 3072 + u0 + 4 * p);
        wi[p] = *(const f32x4*)(wc + u0 + 4 * p);
        wo[p] = *(const f32x4*)(wc + 2048 + u0 + 4 * p);
      }
    }

    f32x4 acc[4][6];
#pragma unroll
    for (int mt = 0; mt < 4; ++mt)
#pragma unroll
      for (int nt = 0; nt < 6; ++nt)
        acc[mt][nt] = (f32x4){0.f, 0.f, 0.f, 0.f};

    const f16* Aw = Abase + wv * Kq + quad * 8;
    if (grp == 0) gemm96<512>(Aw, Breg, lr, acc);
    else          gemm96<1024>(Aw, Breg, lr, acc);

    // cross-wave K-partial reduce via LDS (cols: i 0-31, g 32-63, o 64-95)
#pragma unroll
    for (int mt = 0; mt < 4; ++mt)
#pragma unroll
      for (int nt = 0; nt < 6; ++nt)
#pragma unroll
        for (int r = 0; r < 4; ++r)
          lds[wv][mt * 16 + quad * 4 + r][nt * 16 + lr] = acc[mt][nt][r];
    __syncthreads();

    f32x4 hv[2], cn[2];                // live past flag for grp3 out-stores
    if ((grp & 1) == 0) {
      // P-group epilogue: 64x96 fp32 tile -> ring; 8B atomic stores, lanes
      // cover contiguous runs (full-line write-through).
      float* Pb = (grp == 0 ? P0b : P1b) + (size_t)(t & (PRING - 1)) * NB * 3072;
#pragma unroll
      for (int r = 0; r < 12; ++r) {
        const int s  = r * 256 + tid;        // 3072 col-pairs
        const int m  = s / 48, cp = s - m * 48;
        const int c0 = cp << 1;
        float v0 = lds[0][m][c0]     + lds[1][m][c0]     + lds[2][m][c0]     + lds[3][m][c0];
        float v1 = lds[0][m][c0 + 1] + lds[1][m][c0 + 1] + lds[2][m][c0 + 1] + lds[3][m][c0 + 1];
        union { float f[2]; unsigned long long u; } pp; pp.f[0] = v0; pp.f[1] = v1;
        st8a(Pb + (size_t)m * 3072 + ug * 96 + c0, pp.u);
      }
    } else {
      // L-group epilogue: 8 contiguous units per thread (2x f32x4 lanes)
      f32x4 vi[2], vg[2], vo[2];
#pragma unroll
      for (int p = 0; p < 2; ++p) { vi[p] = (f32x4){0,0,0,0}; vg[p] = vi[p]; vo[p] = vi[p]; }
#pragma unroll
      for (int w = 0; w < 4; ++w)
#pragma unroll
        for (int p = 0; p < 2; ++p) {
          vi[p] += *(const f32x4*)&lds[w][m_e][j0 + 4 * p];
          vg[p] += *(const f32x4*)&lds[w][m_e][32 + j0 + 4 * p];
          vo[p] += *(const f32x4*)&lds[w][m_e][64 + j0 + 4 * p];
        }
      float pif[8], pgf[8], pof[8];
      union { unsigned long long u; float f[2]; } qq;
#pragma unroll
      for (int q = 0; q < 4; ++q) {
        qq.u = pri[q]; pif[2*q] = qq.f[0]; pif[2*q+1] = qq.f[1];
        qq.u = prg[q]; pgf[2*q] = qq.f[0]; pgf[2*q+1] = qq.f[1];
        qq.u = pro[q]; pof[2*q] = qq.f[0]; pof[2*q+1] = qq.f[1];
      }
      f16* Hdst = (grp == 1 ? H0 : H1) + (size_t)(t + 1) * NB * HDIM;
#pragma unroll
      for (int p = 0; p < 2; ++p)
#pragma unroll
        for (int k = 0; k < 4; ++k) {
          const int e = 4 * p + k;
          float gi = vi[p][k] + pif[e] + bi[p][k];
          float gg = vg[p][k] + pgf[e] + bg[p][k];
          float go = vo[p][k] + pof[e] + bo[p][k];
          float cold = c4[p][k];
          float iv = sigm(gi + wi[p][k] * cold);         // i peephole Wc[0]
          float gv = tanhfast(gg);                       // g
          float ov = sigm(go + wo[p][k] * cold);         // o peephole Wc[2]
          cn[p][k] = gv * (cold + iv);     // faithful: ct = g*c + i*g
          hv[p][k] = ov * tanhfast(cold);  // faithful: uses OLD cell state
        }
#pragma unroll
      for (int p = 0; p < 2; ++p) {
        *(f32x4*)(crow + 4 * p) = cn[p];
        st8a(&Hdst[(size_t)m_e * HDIM + u0 + 4 * p],
             packh4(hv[p][0], hv[p][1], hv[p][2], hv[p][3]));
      }
    }

    // drain sc1 data stores, then signal arrival (plain epoch store, no RMW)
    __builtin_amdgcn_s_waitcnt(0);
    __syncthreads();
    if (tid == 0) sti(FLG(grp, ug), t + 1);

    // grp3 output stores AFTER the flag: HBM ack off the h1 recurrence loop
    if (grp == 3) {
      float* ob = &out[(size_t)m_e * (T_STEPS * HDIM) + (size_t)t * HDIM + u0];
      *(f32x4*)ob = hv[0];
      *(f32x4*)(ob + 4) = hv[1];
      if (t == T_STEPS - 1) {
        float* hf = &out[(size_t)NB * T_STEPS * HDIM + (size_t)m_e * HDIM + u0];
        float* cf = hf + (size_t)NB * HDIM;
        *(f32x4*)hf = hv[0]; *(f32x4*)(hf + 4) = hv[1];
        *(f32x4*)cf = cn[0]; *(f32x4*)(cf + 4) = cn[1];
      }
    }
  }
}

extern "C" void kernel_launch(void* const* d_in, const int* in_sizes, int n_in,
                              void* d_out, int out_size, void* d_ws, size_t ws_size,
                              hipStream_t stream) {
  const float* x   = (const float*)d_in[0];
  const float* Wx0 = (const float*)d_in[1];
  const float* Wh0 = (const float*)d_in[2];
  const float* b0  = (const float*)d_in[3];
  const float* Wc0 = (const float*)d_in[4];
  const float* Wx1 = (const float*)d_in[5];
  const float* Wh1 = (const float*)d_in[6];
  const float* b1  = (const float*)d_in[7];
  const float* Wc1 = (const float*)d_in[8];
  char* ws = (char*)d_ws;

  // ws re-poisoned before each timed launch: zero counters/flags + initial state
  hipMemsetAsync(ws + CNT_OFF, 0, 81920, stream);              // proCnt + flags
  hipMemsetAsync(ws + H0_OFF, 0, NB * HDIM * 2, stream);       // h0_{-1} = 0 (slot 0)
  hipMemsetAsync(ws + H1_OFF, 0, NB * HDIM * 2, stream);       // h1_{-1} = 0 (slot 0)
  hipMemsetAsync(ws + C0_OFF, 0, 2 * NB * HDIM * 4, stream);   // c0, c1 = 0 (contiguous)

  hipLaunchKernelGGL(lstm_pers, dim3(NWG), dim3(TPB), 0, stream,
                     x, Wx0, Wh0, b0, Wc0, Wx1, Wh1, b1, Wc1,
                     (float*)d_out, ws);
}

// Round 11
// 2143.033 us; speedup vs baseline: 1.4487x; 1.4487x over previous
//
#include <hip/hip_runtime.h>
#include <stdint.h>

// Fence-free dataflow-pipelined persistent LSTM, MI355X — v9.
// v7c (2159 us, PASS) -> v8 (3105 us REGRESSION: fat-WG spilled at the 256-
// VGPR arch cap, halved occupancy, no clock gain — refuted) -> v9: back to
// v7c structure exactly, plus:
//  1. BUSY-POLL: every flag poll replaces s_sleep(1) with a 32-FMA dummy
//     burst (same ~64cy poll period, same MALL poll rate, but waves ISSUE
//     continuously). Counter arithmetic on v7c (96 MFMA x 5cy = 480cy/step vs
//     MfmaUtil 6.9% -> ~7000cy/step at 8.4us) implies effective clock
//     ~0.83 GHz — DPM-depressed at 8% VALUBusy. Busy-polling raises apparent
//     duty with ZERO added latency on the critical chain.
//  2. c-state REGISTER-RESIDENT across all 256 steps (thread-private f32x4;
//     initial c = 0). Deletes c-load from prefetch + c-store from drain
//     scope; C0/C1 buffers and their memset deleted.
// Everything else = v7c: register-resident weights (Breg[3][8], predicated
// static fill), 64B-stride WG flags, composite per-wave detect, post-epilogue
// waitcnt(0)+barrier+tid0 flag, grp3 out-stores after flag.
// Sync semantics: RELAXED agent atomics only; cross-WG data via sc1
// write-through stores drained before flag; h/x read via normal cached loads
// at never-touched addresses; P rings via atomic loads.
// f-gate dead code (reference quirk) -> [i|g|o] = 48 gate rows per 16 units.

#define T_STEPS 256
#define HDIM    1024
#define NB      64
#define INDIM   512
#define NWG     256
#define TPB     256
#define PRING   8

typedef _Float16 f16;
typedef __attribute__((ext_vector_type(8))) _Float16 f16x8;
typedef __attribute__((ext_vector_type(4))) float    f32x4;

// ws byte offsets
#define CNT_OFF 0            // proCnt @0; WG flags @ +64B: [4][64] ints, 64B stride
#define XB_OFF  81920        // f16 [256][64][512]   x, time-major
#define H0_OFF  16859136     // f16 [257][64][1024]  slot t = h0_{t-1}
#define H1_OFF  50544640     // f16 [257][64][1024]  slot t = h1_{t-1}
#define P0_OFF  84754432     // f32 [8][64][3072]    ring, [slot][m][col]
#define P1_OFF  91045888     // f32 [8][64][3072]
// end 97337344

__device__ __forceinline__ float sigm(float x)     { return 1.0f / (1.0f + __expf(-x)); }
__device__ __forceinline__ float tanhfast(float x) { float e = __expf(2.0f * x); return 1.0f - 2.0f / (e + 1.0f); }

__device__ __forceinline__ void arrive(int* c) {
  __hip_atomic_fetch_add(c, 1, __ATOMIC_RELAXED, __HIP_MEMORY_SCOPE_AGENT);
}
// busy-poll: keeps the wave ISSUING between flag checks (DPM sees activity);
// ~64cy per burst = same poll period as the old s_sleep(1).
__device__ __forceinline__ void poll_ge(int* p, int tgt) {
  if (__hip_atomic_load(p, __ATOMIC_RELAXED, __HIP_MEMORY_SCOPE_AGENT) >= tgt) return;
  float d = 1.0f;
  for (;;) {
#pragma unroll
    for (int i = 0; i < 32; ++i)
      d = __builtin_fmaf(d, 1.0000001f, 1e-30f);
    asm volatile("" : "+v"(d));            // keep burst alive, no side effects
    if (__hip_atomic_load(p, __ATOMIC_RELAXED, __HIP_MEMORY_SCOPE_AGENT) >= tgt) return;
  }
}
__device__ __forceinline__ void sti(int* p, int v) {
  __hip_atomic_store(p, v, __ATOMIC_RELAXED, __HIP_MEMORY_SCOPE_AGENT);
}
__device__ __forceinline__ void st2h(f16* p, float a, float b) {
  union { f16 h[2]; uint32_t u; } cc; cc.h[0] = (f16)a; cc.h[1] = (f16)b;
  __hip_atomic_store((uint32_t*)p, cc.u, __ATOMIC_RELAXED, __HIP_MEMORY_SCOPE_AGENT);
}
__device__ __forceinline__ void st8a(void* p, unsigned long long v) {
  __hip_atomic_store((unsigned long long*)p, v, __ATOMIC_RELAXED, __HIP_MEMORY_SCOPE_AGENT);
}
__device__ __forceinline__ unsigned long long ld8(const float* p) {
  return __hip_atomic_load((const unsigned long long*)p, __ATOMIC_RELAXED, __HIP_MEMORY_SCOPE_AGENT);
}
__device__ __forceinline__ f16x8 pack8(f32x4 a, f32x4 b) {
  f16x8 h;
  h[0]=(f16)a[0]; h[1]=(f16)a[1]; h[2]=(f16)a[2]; h[3]=(f16)a[3];
  h[4]=(f16)b[0]; h[5]=(f16)b[1]; h[6]=(f16)b[2]; h[7]=(f16)b[3];
  return h;
}

// 48x64 tile GEMM: A from global (f16, row stride K), B register-resident.
template<int K>
__device__ __forceinline__ void gemm48_regB(const f16* __restrict__ Aw,
                                            const f16x8 (&B)[3][8],
                                            int lr, f32x4 (&acc)[4][3]) {
  constexpr int NIT = K / 128;                 // per-wave K-quarter, 32/iter
  const f16* a0 = Aw + (size_t)(lr +  0) * K;
  const f16* a1 = Aw + (size_t)(lr + 16) * K;
  const f16* a2 = Aw + (size_t)(lr + 32) * K;
  const f16* a3 = Aw + (size_t)(lr + 48) * K;
  f16x8 A0[NIT], A1[NIT], A2[NIT], A3[NIT];
#pragma unroll
  for (int it = 0; it < NIT; ++it) {
    const int kk = it * 32;
    A0[it] = *(const f16x8*)(a0 + kk);
    A1[it] = *(const f16x8*)(a1 + kk);
    A2[it] = *(const f16x8*)(a2 + kk);
    A3[it] = *(const f16x8*)(a3 + kk);
  }
#pragma unroll
  for (int it = 0; it < NIT; ++it) {
    acc[0][0] = __builtin_amdgcn_mfma_f32_16x16x32_f16(A0[it], B[0][it], acc[0][0], 0, 0, 0);
    acc[0][1] = __builtin_amdgcn_mfma_f32_16x16x32_f16(A0[it], B[1][it], acc[0][1], 0, 0, 0);
    acc[0][2] = __builtin_amdgcn_mfma_f32_16x16x32_f16(A0[it], B[2][it], acc[0][2], 0, 0, 0);
    acc[1][0] = __builtin_amdgcn_mfma_f32_16x16x32_f16(A1[it], B[0][it], acc[1][0], 0, 0, 0);
    acc[1][1] = __builtin_amdgcn_mfma_f32_16x16x32_f16(A1[it], B[1][it], acc[1][1], 0, 0, 0);
    acc[1][2] = __builtin_amdgcn_mfma_f32_16x16x32_f16(A1[it], B[2][it], acc[1][2], 0, 0, 0);
    acc[2][0] = __builtin_amdgcn_mfma_f32_16x16x32_f16(A2[it], B[0][it], acc[2][0], 0, 0, 0);
    acc[2][1] = __builtin_amdgcn_mfma_f32_16x16x32_f16(A2[it], B[1][it], acc[2][1], 0, 0, 0);
    acc[2][2] = __builtin_amdgcn_mfma_f32_16x16x32_f16(A2[it], B[2][it], acc[2][2], 0, 0, 0);
    acc[3][0] = __builtin_amdgcn_mfma_f32_16x16x32_f16(A3[it], B[0][it], acc[3][0], 0, 0, 0);
    acc[3][1] = __builtin_amdgcn_mfma_f32_16x16x32_f16(A3[it], B[1][it], acc[3][1], 0, 0, 0);
    acc[3][2] = __builtin_amdgcn_mfma_f32_16x16x32_f16(A3[it], B[2][it], acc[3][2], 0, 0, 0);
  }
}

__global__ __launch_bounds__(TPB, 1) void lstm_pers(
    const float* __restrict__ x,
    const float* __restrict__ Wx0, const float* __restrict__ Wh0,
    const float* __restrict__ b0,  const float* __restrict__ Wc0,
    const float* __restrict__ Wx1, const float* __restrict__ Wh1,
    const float* __restrict__ b1,  const float* __restrict__ Wc1,
    float* __restrict__ out, char* __restrict__ ws)
{
  int* cbase = (int*)(ws + CNT_OFF);
  int* proCnt = cbase;
  auto FLG = [&](int g, int i) { return cbase + 16 + ((g * 64 + i) << 4); };  // 64B stride

  f16* XB   = (f16*)(ws + XB_OFF);
  f16* H0   = (f16*)(ws + H0_OFF);
  f16* H1   = (f16*)(ws + H1_OFF);
  float* P0b = (float*)(ws + P0_OFF);
  float* P1b = (float*)(ws + P1_OFF);

  __shared__ float lds[4][64][52];     // cross-wave K-partial reduce (53248 B)

  const int tid  = threadIdx.x;
  const int wg   = blockIdx.x;
  const int gtid = wg * TPB + tid;
  const int GSZ  = NWG * TPB;

  const int grp  = wg >> 6;      // 0=P0, 1=L0, 2=P1, 3=L1
  const int ug   = wg & 63;
  const int lane = tid & 63;
  const int wv   = tid >> 6;
  const int quad = lane >> 4;
  const int lr   = lane & 15;

  const float* Wsrc; int K;
  switch (grp) {
    case 0:  Wsrc = Wx0; K = 512;  break;
    case 1:  Wsrc = Wh0; K = 1024; break;
    case 2:  Wsrc = Wx1; K = 1024; break;
    default: Wsrc = Wh1; K = 1024; break;
  }
  const int Kq  = K >> 2;
  const int NIT = K >> 7;        // 4 (K=512) or 8 (K=1024)

  // ---------------- prologue ----------------
  // (a) per-wave weight quarter -> REGISTERS (held across all 256 steps).
  //     Compile-time-bounded predicated fill -> static indexing, no scratch.
  f16x8 Breg[3][8];
#pragma unroll
  for (int nt = 0; nt < 3; ++nt) {
    const int R = ug * 16 + lr + (nt == 1 ? 2048 : (nt == 2 ? 3072 : 0));
    const float* wr = Wsrc + (size_t)R * K + wv * Kq + quad * 8;
#pragma unroll
    for (int it = 0; it < 8; ++it) {
      if (it < NIT) {
        f32x4 f0 = *(const f32x4*)(wr + it * 32);
        f32x4 f1 = *(const f32x4*)(wr + it * 32 + 4);
        Breg[nt][it] = pack8(f0, f1);
      } else {
        Breg[nt][it] = (f16x8){};
      }
    }
  }
  // (b) x pack, time-major, proven 4B sc1 atomic pair stores
  for (int idx = gtid; idx < T_STEPS * NB * 256; idx += GSZ) {
    int t = idx >> 14, n = (idx >> 8) & 63, i2 = (idx & 255) << 1;
    const float* src = x + (size_t)n * (T_STEPS * INDIM) + (size_t)t * INDIM + i2;
    st2h(&XB[(size_t)idx << 1], src[0], src[1]);
  }

  // light grid barrier (no cache fences; shared data went through sc1)
  __builtin_amdgcn_s_waitcnt(0);
  __syncthreads();
  if (tid == 0) { arrive(proCnt); poll_ge(proCnt, NWG); }
  __syncthreads();

  // ---------------- persistent 4-group dataflow pipeline ----------------
  const int m_e = tid >> 2, j0 = (tid & 3) << 2;   // L-epilogue coords
  const int u0  = ug * 16 + j0;

  // hoisted per-thread L-epilogue constants (bias, peephole) + c-state REGS
  f32x4 b_i{}, b_g{}, b_o{}, wci{}, wco{};
  f32x4 c4 = (f32x4){0.f, 0.f, 0.f, 0.f};   // c_{-1} = 0, lives in regs
  if (grp & 1) {
    const float* bb = (grp == 1) ? b0 : b1;
    const float* wc = (grp == 1) ? Wc0 : Wc1;
    b_i = *(const f32x4*)(bb + u0);
    b_g = *(const f32x4*)(bb + 2048 + u0);
    b_o = *(const f32x4*)(bb + 3072 + u0);
    wci = *(const f32x4*)(wc + u0);
    wco = *(const f32x4*)(wc + 2048 + u0);
  }

  for (int t = 0; t < T_STEPS; ++t) {
    // ---- per-wave composite detect (no barrier; 64B-stride WG flags) ----
    {
      int* myp = nullptr; int tgt = 0;
      if (grp == 0) {
        if (lane == 0 && t >= PRING) { myp = FLG(1, ug); tgt = t - PRING + 1; }
      } else if (grp == 1) {
        if (lane < 16 && t > 0)      { myp = FLG(1, wv * 16 + lr); tgt = t; }
        else if (lane == 16)         { myp = FLG(0, ug); tgt = t + 1; }
      } else if (grp == 2) {
        if (lane < 16)               { myp = FLG(1, wv * 16 + lr); tgt = t + 1; }
        else if (lane == 16 && t >= PRING) { myp = FLG(3, ug); tgt = t - PRING + 1; }
      } else {
        if (lane < 16 && t > 0)      { myp = FLG(3, wv * 16 + lr); tgt = t; }
        else if (lane == 16)         { myp = FLG(2, ug); tgt = t + 1; }
      }
      if (myp) poll_ge(myp, tgt);
      __atomic_signal_fence(__ATOMIC_ACQUIRE);
    }

    const f16* Abase;
    if (grp == 0)      Abase = XB + (size_t)t * NB * INDIM;          // x_t
    else if (grp == 1) Abase = H0 + (size_t)t * NB * HDIM;           // h0_{t-1}
    else if (grp == 2) Abase = H0 + (size_t)(t + 1) * NB * HDIM;     // h0_t
    else               Abase = H1 + (size_t)t * NB * HDIM;           // h1_{t-1}

    // L-groups: issue P-ring gate loads NOW; latency hides under the GEMM.
    unsigned long long pr0, pr1, pr2, pr3, pr4, pr5;
    if (grp & 1) {
      const float* Pb = (grp == 1 ? P0b : P1b) + (size_t)(t & (PRING - 1)) * NB * 3072;
      const float* pbase = Pb + (size_t)m_e * 3072 + ug * 48 + j0;
      pr0 = ld8(pbase);      pr1 = ld8(pbase + 2);    // i gate cols j0..j0+3
      pr2 = ld8(pbase + 16); pr3 = ld8(pbase + 18);   // g gate
      pr4 = ld8(pbase + 32); pr5 = ld8(pbase + 34);   // o gate
    }

    f32x4 acc[4][3];
#pragma unroll
    for (int mt = 0; mt < 4; ++mt)
#pragma unroll
      for (int nt = 0; nt < 3; ++nt)
        acc[mt][nt] = (f32x4){0.f, 0.f, 0.f, 0.f};

    const f16* Aw = Abase + wv * Kq + quad * 8;
    if (grp == 0) gemm48_regB<512>(Aw, Breg, lr, acc);
    else          gemm48_regB<1024>(Aw, Breg, lr, acc);

    // cross-wave K-partial reduce via LDS
#pragma unroll
    for (int mt = 0; mt < 4; ++mt)
#pragma unroll
      for (int nt = 0; nt < 3; ++nt)
#pragma unroll
        for (int r = 0; r < 4; ++r)
          lds[wv][mt * 16 + quad * 4 + r][nt * 16 + lr] = acc[mt][nt][r];
    __syncthreads();

    f32x4 hv;                          // live past flag for grp3 out-stores
    if ((grp & 1) == 0) {
      // P-group epilogue: 64x48 fp32 tile -> ring; 8B atomic stores, lanes
      // cover contiguous 192B runs per instruction (full-line write-through).
      float* Pb = (grp == 0 ? P0b : P1b) + (size_t)(t & (PRING - 1)) * NB * 3072;
#pragma unroll
      for (int r = 0; r < 6; ++r) {
        const int s  = r * 256 + tid;        // 1536 col-pairs
        const int m  = s / 24, cp = s - m * 24;
        const int c0 = cp << 1;
        float v0 = lds[0][m][c0]     + lds[1][m][c0]     + lds[2][m][c0]     + lds[3][m][c0];
        float v1 = lds[0][m][c0 + 1] + lds[1][m][c0 + 1] + lds[2][m][c0 + 1] + lds[3][m][c0 + 1];
        union { float f[2]; unsigned long long u; } pp; pp.f[0] = v0; pp.f[1] = v1;
        st8a(Pb + (size_t)m * 3072 + ug * 48 + c0, pp.u);
      }
    } else {
      // L-group epilogue: 4 contiguous units per thread; LDS via ds_read_b128
      union { unsigned long long u; float f[2]; } q0, q1, q2, q3, q4, q5;
      q0.u = pr0; q1.u = pr1; q2.u = pr2; q3.u = pr3; q4.u = pr4; q5.u = pr5;
      f32x4 vi = (f32x4){0.f, 0.f, 0.f, 0.f};
      f32x4 vg = vi, vo = vi;
#pragma unroll
      for (int w = 0; w < 4; ++w) {
        vi += *(const f32x4*)&lds[w][m_e][j0];
        vg += *(const f32x4*)&lds[w][m_e][16 + j0];
        vo += *(const f32x4*)&lds[w][m_e][32 + j0];
      }
      const float pif[4] = {q0.f[0], q0.f[1], q1.f[0], q1.f[1]};
      const float pgf[4] = {q2.f[0], q2.f[1], q3.f[0], q3.f[1]};
      const float pof[4] = {q4.f[0], q4.f[1], q5.f[0], q5.f[1]};
      f16* Hdst = (grp == 1 ? H0 : H1) + (size_t)(t + 1) * NB * HDIM;
      f32x4 cn;
#pragma unroll
      for (int k = 0; k < 4; ++k) {
        float gi = vi[k] + pif[k] + b_i[k];
        float gg = vg[k] + pgf[k] + b_g[k];
        float go = vo[k] + pof[k] + b_o[k];
        float cold = c4[k];
        float iv = sigm(gi + wci[k] * cold);           // i peephole Wc[0]
        float gv = tanhfast(gg);                       // g
        float ov = sigm(go + wco[k] * cold);           // o peephole Wc[2]
        cn[k] = gv * (cold + iv);     // faithful: ct = g*c + i*g
        hv[k] = ov * tanhfast(cold);  // faithful: uses OLD cell state
      }
      c4 = cn;                        // c-state carried in registers
      union { f16 h[4]; unsigned long long u; } hh;
      hh.h[0]=(f16)hv[0]; hh.h[1]=(f16)hv[1]; hh.h[2]=(f16)hv[2]; hh.h[3]=(f16)hv[3];
      st8a(&Hdst[(size_t)m_e * HDIM + u0], hh.u);
    }

    // drain sc1 data stores, then signal arrival (plain epoch store, no RMW)
    __builtin_amdgcn_s_waitcnt(0);
    __syncthreads();
    if (tid == 0) sti(FLG(grp, ug), t + 1);

    // grp3 output stores AFTER the flag: HBM ack off the h1 recurrence loop
    if (grp == 3) {
      *(f32x4*)&out[(size_t)m_e * (T_STEPS * HDIM) + (size_t)t * HDIM + u0] = hv;
      if (t == T_STEPS - 1) {
        *(f32x4*)&out[(size_t)NB * T_STEPS * HDIM + (size_t)m_e * HDIM + u0] = hv;
        *(f32x4*)&out[(size_t)NB * T_STEPS * HDIM + NB * HDIM + (size_t)m_e * HDIM + u0] = c4;
      }
    }
  }
}

extern "C" void kernel_launch(void* const* d_in, const int* in_sizes, int n_in,
                              void* d_out, int out_size, void* d_ws, size_t ws_size,
                              hipStream_t stream) {
  const float* x   = (const float*)d_in[0];
  const float* Wx0 = (const float*)d_in[1];
  const float* Wh0 = (const float*)d_in[2];
  const float* b0  = (const float*)d_in[3];
  const float* Wc0 = (const float*)d_in[4];
  const float* Wx1 = (const float*)d_in[5];
  const float* Wh1 = (const float*)d_in[6];
  const float* b1  = (const float*)d_in[7];
  const float* Wc1 = (const float*)d_in[8];
  char* ws = (char*)d_ws;

  // ws re-poisoned before each timed launch: zero counters/flags + initial h
  hipMemsetAsync(ws + CNT_OFF, 0, 81920, stream);              // proCnt + flags
  hipMemsetAsync(ws + H0_OFF, 0, NB * HDIM * 2, stream);       // h0_{-1} = 0 (slot 0)
  hipMemsetAsync(ws + H1_OFF, 0, NB * HDIM * 2, stream);       // h1_{-1} = 0 (slot 0)

  hipLaunchKernelGGL(lstm_pers, dim3(NWG), dim3(TPB), 0, stream,
                     x, Wx0, Wh0, b0, Wc0, Wx1, Wh1, b1, Wc1,
                     (float*)d_out, ws);
}